// Round 9
// baseline (167.830 us; speedup 1.0000x reference)
//
#include <hip/hip_runtime.h>
#include <hip/hip_bf16.h>

#define DEVINL __device__ __forceinline__

typedef __attribute__((ext_vector_type(8))) short short8;
typedef __attribute__((ext_vector_type(4))) float f32x4;

DEVINL unsigned short f2bf(float x) {
  __hip_bfloat16 h = __float2bfloat16(x);
  return __builtin_bit_cast(unsigned short, h);
}
DEVINL unsigned int pk2(float lo, float hi) {
  return (unsigned int)f2bf(lo) | ((unsigned int)f2bf(hi) << 16);
}
DEVINL float bf2f(unsigned short h) {
  union { unsigned int u; float f; } c; c.u = ((unsigned int)h) << 16;
  return c.f;
}
// tanh-form GELU (branchless): |diff vs erf-GELU| <~3e-3, far under threshold.
DEVINL float gelu_f(float x) {
  const float u = x * x;
  const float y = x * (0.7978845608f + 0.0356774081f * u);
  const float e = __expf(-2.0f * y);
  return x * __builtin_amdgcn_rcpf(1.0f + e);
}
DEVINL f32x4 mfma16(short8 a, short8 b, f32x4 c) {
  return __builtin_amdgcn_mfma_f32_16x16x32_bf16(a, b, c, 0, 0, 0);
}

// Dual-chain 16x128 GEMM from two wave-private LDS tiles; B-frags shared.
DEVINL void gemm_w2(const unsigned short* MsA, const unsigned short* MsB,
                    const unsigned short* __restrict__ Wp, int lane,
                    f32x4 (&accA)[8], f32x4 (&accB)[8])
{
  const int rr = lane & 15;
  const int kg = (lane >> 4) << 3;
  __builtin_amdgcn_s_setprio(1);
  #pragma unroll
  for (int t = 0; t < 4; ++t) {
    const short8 aA = *(const short8*)(MsA + rr * 136 + t * 32 + kg);
    const short8 aB = *(const short8*)(MsB + rr * 136 + t * 32 + kg);
    #pragma unroll
    for (int c = 0; c < 8; ++c) {
      const short8 bf = *(const short8*)(Wp + ((size_t)(t * 8 + c) * 64 + lane) * 8);
      accA[c] = mfma16(aA, bf, accA[c]);
      accB[c] = mfma16(aB, bf, accB[c]);
    }
  }
  __builtin_amdgcn_s_setprio(0);
}

// gelu + transpose C-layout -> A-layout into wave-private LDS tile.
DEVINL void epi_gelu(unsigned short* Ms, int lane, f32x4 (&acc)[8])
{
  const int rr = lane & 15;
  const int g4 = (lane >> 4) << 2;
  #pragma unroll
  for (int c = 0; c < 8; ++c)
    #pragma unroll
    for (int r = 0; r < 4; ++r)
      Ms[(g4 + r) * 136 + c * 16 + rr] = f2bf(gelu_f(acc[c][r]));
}

// ---- pack all weights -> bf16 MFMA B-fragments in ws ------------------------
__global__ __launch_bounds__(256) void k_pack(
    const float* __restrict__ W1w,  const float* __restrict__ W2w,
    const float* __restrict__ W3w,  const float* __restrict__ W11w,
    const float* __restrict__ W12w, const float* __restrict__ W13w,
    const float* __restrict__ Winw, const float* __restrict__ Woutw,
    unsigned short* __restrict__ dst)
{
  const int f = blockIdx.x * 256 + threadIdx.x;
  if (f >= 36864) return;
  const float* src; int row0 = 0, Ncols = 128, NT = 8, lf;
  if (f < 20480) {
    const int seg = f >> 11; lf = f & 2047;
    switch (seg) {
      case 0: src = W1w;  row0 = 0;   break;
      case 1: src = W1w;  row0 = 128; break;
      case 2: src = W1w;  row0 = 256; break;
      case 3: src = W2w;  break;
      case 4: src = W3w;  break;
      case 5: src = W11w; row0 = 0;   break;
      case 6: src = W11w; row0 = 128; break;
      case 7: src = W11w; row0 = 256; break;
      case 8: src = W12w; break;
      default: src = W13w; break;
    }
  } else if (f < 28672) { src = Winw; lf = f - 20480; NT = 32; Ncols = 512; }
  else { src = Woutw; lf = f - 28672; }
  const int l = lf & 63;
  const int g = lf >> 6;
  const int c = g % NT;
  const int t = g / NT;
  const int r0 = row0 + t * 32 + ((l >> 4) << 3);
  const int col = c * 16 + (l & 15);
  short8 vv;
  #pragma unroll
  for (int b = 0; b < 8; ++b)
    vv[b] = (short)f2bf(src[(size_t)(r0 + b) * Ncols + col]);
  *(short8*)(dst + (size_t)f * 8) = vv;
}

// ---- precompute P1 = X@Wtop + bias (f32), P3 = X@Wbot (bf16), X:[4096,128] --
__global__ __launch_bounds__(256) void k_pre(
    const float* __restrict__ X,
    const unsigned short* __restrict__ Wtp,
    const unsigned short* __restrict__ Wbp,
    const float* __restrict__ bias,
    float* __restrict__ P1, unsigned short* __restrict__ P3)
{
  __shared__ __align__(16) unsigned short Xs2[16 * 136];
  const int tid = threadIdx.x;
  const int lane = tid & 63;
  const int w = tid >> 6;
  const int rr = lane & 15;
  const int kg = (lane >> 4) << 3;
  const int row0 = blockIdx.x * 16;

  for (int e = tid; e < 512; e += 256) {
    const int r = e >> 5, q = (e & 31) << 2;
    float4 v = *(const float4*)(X + (size_t)(row0 + r) * 128 + q);
    uint2 pk; pk.x = pk2(v.x, v.y); pk.y = pk2(v.z, v.w);
    *(uint2*)(&Xs2[r * 136 + q]) = pk;
  }
  __syncthreads();

  const f32x4 zf = {0.f, 0.f, 0.f, 0.f};
  f32x4 a0[2] = {zf, zf}, a1[2] = {zf, zf};
  #pragma unroll
  for (int t = 0; t < 4; ++t) {
    const short8 a = *(const short8*)(&Xs2[rr * 136 + t * 32 + kg]);
    #pragma unroll
    for (int c = 0; c < 2; ++c) {
      short8 bt = *(const short8*)(Wtp + ((size_t)(t * 8 + (w * 2 + c)) * 64 + lane) * 8);
      a0[c] = mfma16(a, bt, a0[c]);
      short8 bb = *(const short8*)(Wbp + ((size_t)(t * 8 + (w * 2 + c)) * 64 + lane) * 8);
      a1[c] = mfma16(a, bb, a1[c]);
    }
  }
  #pragma unroll
  for (int c = 0; c < 2; ++c) {
    const int col = w * 32 + c * 16 + rr;
    const float b = bias[col];
    #pragma unroll
    for (int r = 0; r < 4; ++r) {
      const int row = row0 + ((lane >> 4) << 2) + r;
      P1[(size_t)row * 128 + col] = a0[c][r] + b;
      P3[(size_t)row * 128 + col] = f2bf(a1[c][r]);
    }
  }
}

// ====== node: 3 waves/block, each wave runs rows [16w,16w+16) of TWO nodes ===
template<bool HEBW>
__global__ __launch_bounds__(192, 3) void k_node_t(
    const float* __restrict__ hV, const float* __restrict__ hE,
    unsigned short* __restrict__ hEb,
    const int* __restrict__ Eidx, const float* __restrict__ maskA,
    const float* __restrict__ P1g, const unsigned short* __restrict__ P3g,
    const unsigned short* __restrict__ Wmidp,
    const unsigned short* __restrict__ W2p, const float* __restrict__ W2b,
    const unsigned short* __restrict__ W3p, const float* __restrict__ W3b,
    const float* __restrict__ ln1g, const float* __restrict__ ln1b,
    float* __restrict__ hVn1)
{
  __shared__ __align__(16) unsigned short Msw[3][2][16 * 136];
  __shared__ float dhs[2][3][128];

  const int tid = threadIdx.x;
  const int lane = tid & 63;
  const int w = tid >> 6;              // 0..2
  const int rr = lane & 15;
  const int g4 = (lane >> 4) << 2;
  const int kg = (lane >> 4) << 3;
  const int q = (blockIdx.x & 7) * 256 + (blockIdx.x >> 3);   // XCD swizzle, 2048 blocks
  const int nA = 2 * q;
  const int nB = 2 * q + 1;
  const int bbase = nA & ~2047;        // same for nB (pairs don't straddle batch)
  const int R0 = w * 16;
  unsigned short* MsA = &Msw[w][0][0];
  unsigned short* MsB = &Msw[w][1][0];

  // gather this wave's 16 P3 rows for both nodes (wave-private)
  {
    const int rl = lane >> 2;
    const int seg = (lane & 3) << 5;
    const int jA = Eidx[(size_t)nA * 48 + R0 + rl];
    const int jB = Eidx[(size_t)nB * 48 + R0 + rl];
    const unsigned short* sA = P3g + (size_t)(bbase + jA) * 128 + seg;
    const unsigned short* sB = P3g + (size_t)(bbase + jB) * 128 + seg;
    unsigned short* dA = MsA + rl * 136 + seg;
    unsigned short* dB = MsB + rl * 136 + seg;
    #pragma unroll
    for (int u = 0; u < 4; ++u) {
      *(short8*)(dA + u * 8) = *(const short8*)(sA + u * 8);
      *(short8*)(dB + u * 8) = *(const short8*)(sB + u * 8);
    }
  }

  // acc init = P1 + gathered P3 (wave-local LDS, in-order DS pipe)
  f32x4 accA[8], accB[8];
  {
    float p1A[8], p1B[8];
    #pragma unroll
    for (int c = 0; c < 8; ++c) {
      p1A[c] = P1g[(size_t)nA * 128 + c * 16 + rr];
      p1B[c] = P1g[(size_t)nB * 128 + c * 16 + rr];
    }
    #pragma unroll
    for (int c = 0; c < 8; ++c)
      #pragma unroll
      for (int r = 0; r < 4; ++r) {
        accA[c][r] = p1A[c] + bf2f(MsA[(g4 + r) * 136 + c * 16 + rr]);
        accB[c][r] = p1B[c] + bf2f(MsB[(g4 + r) * 136 + c * 16 + rr]);
      }
  }

  // GEMM1: A from hE f32 (inline cvt, side-write hEb); B-frags shared A/B
  {
    const float* ArA = hE + (size_t)nA * 6144 + (R0 + rr) * 128;
    const float* ArB = hE + (size_t)nB * 6144 + (R0 + rr) * 128;
    unsigned short* HrA = hEb + (size_t)nA * 6144 + (R0 + rr) * 128;
    unsigned short* HrB = hEb + (size_t)nB * 6144 + (R0 + rr) * 128;
    __builtin_amdgcn_s_setprio(1);
    #pragma unroll
    for (int t = 0; t < 4; ++t) {
      float4 a0 = *(const float4*)(ArA + t * 32 + kg);
      float4 a1 = *(const float4*)(ArA + t * 32 + kg + 4);
      float4 b0 = *(const float4*)(ArB + t * 32 + kg);
      float4 b1 = *(const float4*)(ArB + t * 32 + kg + 4);
      uint4 pkA, pkB;
      pkA.x = pk2(a0.x, a0.y); pkA.y = pk2(a0.z, a0.w);
      pkA.z = pk2(a1.x, a1.y); pkA.w = pk2(a1.z, a1.w);
      pkB.x = pk2(b0.x, b0.y); pkB.y = pk2(b0.z, b0.w);
      pkB.z = pk2(b1.x, b1.y); pkB.w = pk2(b1.z, b1.w);
      if constexpr (HEBW) {
        *(uint4*)(HrA + t * 32 + kg) = pkA;
        *(uint4*)(HrB + t * 32 + kg) = pkB;
      }
      const short8 aA = __builtin_bit_cast(short8, pkA);
      const short8 aB = __builtin_bit_cast(short8, pkB);
      #pragma unroll
      for (int c = 0; c < 8; ++c) {
        const short8 bf = *(const short8*)(Wmidp + ((size_t)(t * 8 + c) * 64 + lane) * 8);
        accA[c] = mfma16(aA, bf, accA[c]);
        accB[c] = mfma16(aB, bf, accB[c]);
      }
    }
    __builtin_amdgcn_s_setprio(0);
  }
  epi_gelu(MsA, lane, accA);
  epi_gelu(MsB, lane, accB);

  // GEMM2 (bias in C-init, shared between chains)
  #pragma unroll
  for (int c = 0; c < 8; ++c) {
    const float b = W2b[c * 16 + rr];
    accA[c] = (f32x4){b, b, b, b};
    accB[c] = accA[c];
  }
  gemm_w2(MsA, MsB, W2p, lane, accA, accB);
  epi_gelu(MsA, lane, accA);
  epi_gelu(MsB, lane, accB);

  // GEMM3 (bias in C-init)
  #pragma unroll
  for (int c = 0; c < 8; ++c) {
    const float b = W3b[c * 16 + rr];
    accA[c] = (f32x4){b, b, b, b};
    accB[c] = accA[c];
  }
  gemm_w2(MsA, MsB, W3p, lane, accA, accB);

  // masked col-sum per node (intra-wave)
  {
    float mkA[4], mkB[4];
    #pragma unroll
    for (int r = 0; r < 4; ++r) {
      mkA[r] = maskA[(size_t)nA * 48 + R0 + g4 + r];
      mkB[r] = maskA[(size_t)nB * 48 + R0 + g4 + r];
    }
    #pragma unroll
    for (int c = 0; c < 8; ++c) {
      float pA = mkA[0] * accA[c][0] + mkA[1] * accA[c][1]
               + mkA[2] * accA[c][2] + mkA[3] * accA[c][3];
      float pB = mkB[0] * accB[c][0] + mkB[1] * accB[c][1]
               + mkB[2] * accB[c][2] + mkB[3] * accB[c][3];
      pA += __shfl_xor(pA, 16); pA += __shfl_xor(pA, 32);
      pB += __shfl_xor(pB, 16); pB += __shfl_xor(pB, 32);
      if (lane < 16) {
        dhs[0][w][c * 16 + lane] = pA;
        dhs[1][w][c * 16 + lane] = pB;
      }
    }
  }
  __syncthreads();                                   // only barrier

  if (w < 2) {                                       // wave w finalizes node w
    const int node = (w == 0) ? nA : nB;
    const float x0 = hV[(size_t)node * 128 + lane]
                   + (dhs[w][0][lane] + dhs[w][1][lane] + dhs[w][2][lane]) * (1.0f / 30.0f);
    const float x1 = hV[(size_t)node * 128 + 64 + lane]
                   + (dhs[w][0][lane + 64] + dhs[w][1][lane + 64] + dhs[w][2][lane + 64]) * (1.0f / 30.0f);
    float s = x0 + x1, sq = x0 * x0 + x1 * x1;
    #pragma unroll
    for (int msk = 1; msk < 64; msk <<= 1) {
      s += __shfl_xor(s, msk);
      sq += __shfl_xor(sq, msk);
    }
    const float mean = s * (1.f / 128.f);
    const float rstd = rsqrtf(sq * (1.f / 128.f) - mean * mean + 1e-5f);
    hVn1[(size_t)node * 128 + lane]      = (x0 - mean) * rstd * ln1g[lane] + ln1b[lane];
    hVn1[(size_t)node * 128 + 64 + lane] = (x1 - mean) * rstd * ln1g[64 + lane] + ln1b[64 + lane];
  }
}

// ---------------- FFN + LN2 + mask_V -> outV; fused P1/P3 for edge pass ------
__global__ __launch_bounds__(256) void k_ffn(
    const float* __restrict__ hVn1,
    const unsigned short* __restrict__ Winp, const float* __restrict__ Winb,
    const unsigned short* __restrict__ Woutp, const float* __restrict__ Woutb,
    const float* __restrict__ ln2g, const float* __restrict__ ln2b,
    const float* __restrict__ maskV,
    const unsigned short* __restrict__ W11tp, const unsigned short* __restrict__ W11bp,
    const float* __restrict__ W11b,
    float* __restrict__ outV, float* __restrict__ P1, unsigned short* __restrict__ P3)
{
  __shared__ __align__(16) unsigned short Xs2[16 * 136];
  __shared__ __align__(16) unsigned short Ys[16 * 520];
  __shared__ __align__(16) unsigned short Ts[16 * 136];
  __shared__ float Rs[16 * 128];

  const int tid = threadIdx.x;
  const int lane = tid & 63;
  const int w = tid >> 6;
  const int rr = lane & 15;
  const int kg = (lane >> 4) << 3;
  const int row0 = blockIdx.x * 16;

  for (int e = tid; e < 512; e += 256) {
    const int r = e >> 5, q = (e & 31) << 2;
    float4 v = *(const float4*)(hVn1 + (size_t)(row0 + r) * 128 + q);
    uint2 pk; pk.x = pk2(v.x, v.y); pk.y = pk2(v.z, v.w);
    *(uint2*)(&Xs2[r * 136 + q]) = pk;
  }
  __syncthreads();

  const f32x4 zf = {0.f, 0.f, 0.f, 0.f};
  f32x4 acc1[8];
  #pragma unroll
  for (int c = 0; c < 8; ++c) acc1[c] = zf;
  #pragma unroll
  for (int t = 0; t < 4; ++t) {
    const short8 a = *(const short8*)(&Xs2[rr * 136 + t * 32 + kg]);
    #pragma unroll
    for (int c = 0; c < 8; ++c) {
      const short8 bf = *(const short8*)(Winp + ((size_t)(t * 32 + w * 8 + c) * 64 + lane) * 8);
      acc1[c] = mfma16(a, bf, acc1[c]);
    }
  }
  #pragma unroll
  for (int c = 0; c < 8; ++c) {
    const int col = w * 128 + c * 16 + rr;
    const float bias = Winb[col];
    #pragma unroll
    for (int r = 0; r < 4; ++r) {
      const int row = ((lane >> 4) << 2) + r;
      Ys[row * 520 + col] = f2bf(gelu_f(acc1[c][r] + bias));
    }
  }
  __syncthreads();

  f32x4 acc2[2];
  acc2[0] = zf; acc2[1] = zf;
  #pragma unroll 4
  for (int t = 0; t < 16; ++t) {
    const short8 a = *(const short8*)(&Ys[rr * 520 + t * 32 + kg]);
    #pragma unroll
    for (int c = 0; c < 2; ++c) {
      const short8 bf = *(const short8*)(Woutp + ((size_t)(t * 8 + w * 2 + c) * 64 + lane) * 8);
      acc2[c] = mfma16(a, bf, acc2[c]);
    }
  }
  #pragma unroll
  for (int c = 0; c < 2; ++c) {
    const int col = w * 32 + c * 16 + rr;
    const float bias = Woutb[col];
    #pragma unroll
    for (int r = 0; r < 4; ++r) {
      const int row = ((lane >> 4) << 2) + r;
      Rs[row * 128 + col] = acc2[c][r] + bias + hVn1[(size_t)(row0 + row) * 128 + col];
    }
  }
  __syncthreads();

  const float g0 = ln2g[lane], g1 = ln2g[lane + 64];
  const float be0 = ln2b[lane], be1 = ln2b[lane + 64];
  for (int i = 0; i < 4; ++i) {
    const int row = w * 4 + i;
    const int grow = row0 + row;
    const float x0 = Rs[row * 128 + lane], x1 = Rs[row * 128 + 64 + lane];
    float s = x0 + x1, q2 = x0 * x0 + x1 * x1;
    #pragma unroll
    for (int msk = 1; msk < 64; msk <<= 1) {
      s += __shfl_xor(s, msk);
      q2 += __shfl_xor(q2, msk);
    }
    const float mean = s * (1.f / 128.f);
    const float rstd = rsqrtf(q2 * (1.f / 128.f) - mean * mean + 1e-5f);
    const float mv = maskV[grow];
    const float y0 = ((x0 - mean) * rstd * g0 + be0) * mv;
    const float y1 = ((x1 - mean) * rstd * g1 + be1) * mv;
    outV[(size_t)grow * 128 + lane]      = y0;
    outV[(size_t)grow * 128 + 64 + lane] = y1;
    Ts[row * 136 + lane]      = f2bf(y0);
    Ts[row * 136 + 64 + lane] = f2bf(y1);
  }
  __syncthreads();

  // fused k_pre for the edge pass: P1 = outV@W11top + b, P3 = outV@W11bot
  f32x4 a0[2] = {zf, zf}, a1[2] = {zf, zf};
  #pragma unroll
  for (int t = 0; t < 4; ++t) {
    const short8 a = *(const short8*)(&Ts[rr * 136 + t * 32 + kg]);
    #pragma unroll
    for (int c = 0; c < 2; ++c) {
      short8 bt = *(const short8*)(W11tp + ((size_t)(t * 8 + (w * 2 + c)) * 64 + lane) * 8);
      a0[c] = mfma16(a, bt, a0[c]);
      short8 bb = *(const short8*)(W11bp + ((size_t)(t * 8 + (w * 2 + c)) * 64 + lane) * 8);
      a1[c] = mfma16(a, bb, a1[c]);
    }
  }
  #pragma unroll
  for (int c = 0; c < 2; ++c) {
    const int col = w * 32 + c * 16 + rr;
    const float b = W11b[col];
    #pragma unroll
    for (int r = 0; r < 4; ++r) {
      const int row = row0 + ((lane >> 4) << 2) + r;
      P1[(size_t)row * 128 + col] = a0[c][r] + b;
      P3[(size_t)row * 128 + col] = f2bf(a1[c][r]);
    }
  }
}

// ====== edge: 3 waves/block, dual-node chains, ZERO barriers =================
template<bool HEB>
__global__ __launch_bounds__(192, 3) void k_edge_t(
    const float* __restrict__ hE, const unsigned short* __restrict__ hEb,
    const int* __restrict__ Eidx,
    const float* __restrict__ P1g, const unsigned short* __restrict__ P3g,
    const unsigned short* __restrict__ Wmidp,
    const unsigned short* __restrict__ W12p, const float* __restrict__ W12b,
    const unsigned short* __restrict__ W13p, const float* __restrict__ W13b,
    const float* __restrict__ ln3g, const float* __restrict__ ln3b,
    float* __restrict__ outE)
{
  __shared__ __align__(16) unsigned short Msw[3][2][16 * 136];

  const int tid = threadIdx.x;
  const int lane = tid & 63;
  const int w = tid >> 6;
  const int rr = lane & 15;
  const int g4 = (lane >> 4) << 2;
  const int kg = (lane >> 4) << 3;
  const int q = (blockIdx.x & 7) * 256 + (blockIdx.x >> 3);
  const int nA = 2 * q;
  const int nB = 2 * q + 1;
  const int bbase = nA & ~2047;
  const int R0 = w * 16;
  unsigned short* MsA = &Msw[w][0][0];
  unsigned short* MsB = &Msw[w][1][0];

  {
    const int rl = lane >> 2;
    const int seg = (lane & 3) << 5;
    const int jA = Eidx[(size_t)nA * 48 + R0 + rl];
    const int jB = Eidx[(size_t)nB * 48 + R0 + rl];
    const unsigned short* sA = P3g + (size_t)(bbase + jA) * 128 + seg;
    const unsigned short* sB = P3g + (size_t)(bbase + jB) * 128 + seg;
    unsigned short* dA = MsA + rl * 136 + seg;
    unsigned short* dB = MsB + rl * 136 + seg;
    #pragma unroll
    for (int u = 0; u < 4; ++u) {
      *(short8*)(dA + u * 8) = *(const short8*)(sA + u * 8);
      *(short8*)(dB + u * 8) = *(const short8*)(sB + u * 8);
    }
  }

  f32x4 accA[8], accB[8];
  {
    float p1A[8], p1B[8];
    #pragma unroll
    for (int c = 0; c < 8; ++c) {
      p1A[c] = P1g[(size_t)nA * 128 + c * 16 + rr];
      p1B[c] = P1g[(size_t)nB * 128 + c * 16 + rr];
    }
    #pragma unroll
    for (int c = 0; c < 8; ++c)
      #pragma unroll
      for (int r = 0; r < 4; ++r) {
        accA[c][r] = p1A[c] + bf2f(MsA[(g4 + r) * 136 + c * 16 + rr]);
        accB[c][r] = p1B[c] + bf2f(MsB[(g4 + r) * 136 + c * 16 + rr]);
      }
  }

  // GEMM1: A from hEb bf16 (or hE f32 fallback); B-frags shared
  {
    __builtin_amdgcn_s_setprio(1);
    #pragma unroll
    for (int t = 0; t < 4; ++t) {
      short8 aA, aB;
      if constexpr (HEB) {
        aA = *(const short8*)(hEb + (size_t)nA * 6144 + (R0 + rr) * 128 + t * 32 + kg);
        aB = *(const short8*)(hEb + (size_t)nB * 6144 + (R0 + rr) * 128 + t * 32 + kg);
      } else {
        const float* pA = hE + (size_t)nA * 6144 + (R0 + rr) * 128 + t * 32 + kg;
        const float* pB = hE + (size_t)nB * 6144 + (R0 + rr) * 128 + t * 32 + kg;
        float4 a0 = *(const float4*)pA, a1 = *(const float4*)(pA + 4);
        float4 b0 = *(const float4*)pB, b1 = *(const float4*)(pB + 4);
        uint4 pkA, pkB;
        pkA.x = pk2(a0.x, a0.y); pkA.y = pk2(a0.z, a0.w);
        pkA.z = pk2(a1.x, a1.y); pkA.w = pk2(a1.z, a1.w);
        pkB.x = pk2(b0.x, b0.y); pkB.y = pk2(b0.z, b0.w);
        pkB.z = pk2(b1.x, b1.y); pkB.w = pk2(b1.z, b1.w);
        aA = __builtin_bit_cast(short8, pkA);
        aB = __builtin_bit_cast(short8, pkB);
      }
      #pragma unroll
      for (int c = 0; c < 8; ++c) {
        const short8 bf = *(const short8*)(Wmidp + ((size_t)(t * 8 + c) * 64 + lane) * 8);
        accA[c] = mfma16(aA, bf, accA[c]);
        accB[c] = mfma16(aB, bf, accB[c]);
      }
    }
    __builtin_amdgcn_s_setprio(0);
  }
  epi_gelu(MsA, lane, accA);
  epi_gelu(MsB, lane, accB);

  #pragma unroll
  for (int c = 0; c < 8; ++c) {
    const float b = W12b[c * 16 + rr];
    accA[c] = (f32x4){b, b, b, b};
    accB[c] = accA[c];
  }
  gemm_w2(MsA, MsB, W12p, lane, accA, accB);
  epi_gelu(MsA, lane, accA);
  epi_gelu(MsB, lane, accB);

  #pragma unroll
  for (int c = 0; c < 8; ++c) {
    const float b = W13b[c * 16 + rr];
    accA[c] = (f32x4){b, b, b, b};
    accB[c] = accA[c];
  }
  gemm_w2(MsA, MsB, W13p, lane, accA, accB);

  // residual + per-row LN3 + store (intra-wave; rows wave-local)
  float lg[8], lb[8];
  #pragma unroll
  for (int c = 0; c < 8; ++c) {
    lg[c] = ln3g[c * 16 + rr];
    lb[c] = ln3b[c * 16 + rr];
  }
  #pragma unroll
  for (int nsel = 0; nsel < 2; ++nsel) {
    const int node = nsel ? nB : nA;
    f32x4* acc = nsel ? accB : accA;
    #pragma unroll
    for (int r = 0; r < 4; ++r) {
      const int row = R0 + g4 + r;
      const size_t rbase = (size_t)node * 6144 + (size_t)row * 128;
      float v[8];
      float s = 0.f, sq = 0.f;
      #pragma unroll
      for (int c = 0; c < 8; ++c) {
        float res;
        if constexpr (HEB) res = bf2f(hEb[rbase + c * 16 + rr]);
        else               res = hE[rbase + c * 16 + rr];
        v[c] = acc[c][r] + res;
        s += v[c];
        sq += v[c] * v[c];
      }
      s += __shfl_xor(s, 1); sq += __shfl_xor(sq, 1);
      s += __shfl_xor(s, 2); sq += __shfl_xor(sq, 2);
      s += __shfl_xor(s, 4); sq += __shfl_xor(sq, 4);
      s += __shfl_xor(s, 8); sq += __shfl_xor(sq, 8);
      const float mean = s * (1.f / 128.f);
      const float rstd = rsqrtf(sq * (1.f / 128.f) - mean * mean + 1e-5f);
      #pragma unroll
      for (int c = 0; c < 8; ++c)
        outE[rbase + c * 16 + rr] = (v[c] - mean) * rstd * lg[c] + lb[c];
    }
  }
}

extern "C" void kernel_launch(void* const* d_in, const int* in_sizes, int n_in,
                              void* d_out, int out_size, void* d_ws, size_t ws_size,
                              hipStream_t stream) {
  const float* hV    = (const float*)d_in[0];
  const float* hE    = (const float*)d_in[1];
  const int*   Eidx  = (const int*)d_in[2];
  const float* maskV = (const float*)d_in[3];
  const float* maskA = (const float*)d_in[4];
  const float* W1w  = (const float*)d_in[5];  const float* W1b  = (const float*)d_in[6];
  const float* W2w  = (const float*)d_in[7];  const float* W2b  = (const float*)d_in[8];
  const float* W3w  = (const float*)d_in[9];  const float* W3b  = (const float*)d_in[10];
  const float* W11w = (const float*)d_in[11]; const float* W11b = (const float*)d_in[12];
  const float* W12w = (const float*)d_in[13]; const float* W12b = (const float*)d_in[14];
  const float* W13w = (const float*)d_in[15]; const float* W13b = (const float*)d_in[16];
  const float* Winw = (const float*)d_in[17]; const float* Winb = (const float*)d_in[18];
  const float* Woutw= (const float*)d_in[19]; const float* Woutb= (const float*)d_in[20];
  const float* ln1g = (const float*)d_in[21]; const float* ln1b = (const float*)d_in[22];
  const float* ln2g = (const float*)d_in[23]; const float* ln2b = (const float*)d_in[24];
  const float* ln3g = (const float*)d_in[25]; const float* ln3b = (const float*)d_in[26];

  float* outV = (float*)d_out;                       // [4096,128]
  float* outE = outV + (size_t)4096 * 128;           // [4096*48,128]

  char* ws = (char*)d_ws;
  float* hVn1 = (float*)ws;                                  // 2 MB
  float* P1   = (float*)(ws + (size_t)2 * 1024 * 1024);      // 2 MB
  unsigned short* P3 = (unsigned short*)(ws + (size_t)4 * 1024 * 1024);  // 1 MB
  unsigned short* Wp = (unsigned short*)(ws + (size_t)5 * 1024 * 1024);  // 576 KB
  unsigned short* hEb = (unsigned short*)(ws + (size_t)6 * 1024 * 1024); // 48 MB bf16

  const size_t NEED = (size_t)6 * 1024 * 1024 + (size_t)4096 * 48 * 128 * 2;
  const bool heb = ws_size >= NEED;

  const unsigned short* W1top_p  = Wp;
  const unsigned short* W1mid_p  = Wp + (size_t)2048 * 8;
  const unsigned short* W1bot_p  = Wp + (size_t)4096 * 8;
  const unsigned short* W2p      = Wp + (size_t)6144 * 8;
  const unsigned short* W3p      = Wp + (size_t)8192 * 8;
  const unsigned short* W11top_p = Wp + (size_t)10240 * 8;
  const unsigned short* W11mid_p = Wp + (size_t)12288 * 8;
  const unsigned short* W11bot_p = Wp + (size_t)14336 * 8;
  const unsigned short* W12p     = Wp + (size_t)16384 * 8;
  const unsigned short* W13p     = Wp + (size_t)18432 * 8;
  const unsigned short* Winp     = Wp + (size_t)20480 * 8;
  const unsigned short* Woutp    = Wp + (size_t)28672 * 8;

  k_pack<<<144, 256, 0, stream>>>(W1w, W2w, W3w, W11w, W12w, W13w, Winw, Woutw, Wp);
  k_pre<<<256, 256, 0, stream>>>(hV, W1top_p, W1bot_p, W1b, P1, P3);

  if (heb)
    k_node_t<true><<<2048, 192, 0, stream>>>(hV, hE, hEb, Eidx, maskA, P1, P3,
                                             W1mid_p, W2p, W2b, W3p, W3b,
                                             ln1g, ln1b, hVn1);
  else
    k_node_t<false><<<2048, 192, 0, stream>>>(hV, hE, hEb, Eidx, maskA, P1, P3,
                                              W1mid_p, W2p, W2b, W3p, W3b,
                                              ln1g, ln1b, hVn1);

  k_ffn<<<256, 256, 0, stream>>>(hVn1, Winp, Winb, Woutp, Woutb,
                                 ln2g, ln2b, maskV,
                                 W11top_p, W11bot_p, W11b,
                                 outV, P1, P3);

  if (heb)
    k_edge_t<true><<<2048, 192, 0, stream>>>(hE, hEb, Eidx, P1, P3,
                                             W11mid_p, W12p, W12b, W13p, W13b,
                                             ln3g, ln3b, outE);
  else
    k_edge_t<false><<<2048, 192, 0, stream>>>(hE, hEb, Eidx, P1, P3,
                                              W11mid_p, W12p, W12b, W13p, W13b,
                                              ln3g, ln3b, outE);
}

// Round 11
// 139.851 us; speedup vs baseline: 1.2001x; 1.2001x over previous
//
#include <hip/hip_runtime.h>
#include <hip/hip_bf16.h>

#define DEVINL __device__ __forceinline__

typedef __attribute__((ext_vector_type(8))) short short8;
typedef __attribute__((ext_vector_type(4))) float f32x4;

DEVINL unsigned short f2bf(float x) {
  __hip_bfloat16 h = __float2bfloat16(x);
  return __builtin_bit_cast(unsigned short, h);
}
DEVINL unsigned int pk2(float lo, float hi) {
  return (unsigned int)f2bf(lo) | ((unsigned int)f2bf(hi) << 16);
}
DEVINL float bf2f(unsigned short h) {
  union { unsigned int u; float f; } c; c.u = ((unsigned int)h) << 16;
  return c.f;
}
// tanh-form GELU (branchless): |diff vs erf-GELU| <~3e-3, far under threshold.
DEVINL float gelu_f(float x) {
  const float u = x * x;
  const float y = x * (0.7978845608f + 0.0356774081f * u);
  const float e = __expf(-2.0f * y);
  return x * __builtin_amdgcn_rcpf(1.0f + e);
}
DEVINL f32x4 mfma16(short8 a, short8 b, f32x4 c) {
  return __builtin_amdgcn_mfma_f32_16x16x32_bf16(a, b, c, 0, 0, 0);
}

// GEMM from LDS A-tile (row-major, ldx bf16 elems) with pre-packed B frags.
template<int KSTEPS, int MT, int NT>
DEVINL void gemm_tiles(const unsigned short* Xl, int ldx,
                       const unsigned short* __restrict__ Wp,
                       int lane, int w, f32x4 (&acc)[MT][2])
{
  const int rr = lane & 15;
  const int kg = (lane >> 4) << 3;
  __builtin_amdgcn_s_setprio(1);
  #pragma unroll
  for (int t = 0; t < KSTEPS; ++t) {
    short8 a[MT];
    #pragma unroll
    for (int m = 0; m < MT; ++m)
      a[m] = *(const short8*)(Xl + (m * 16 + rr) * ldx + t * 32 + kg);
    #pragma unroll
    for (int c = 0; c < 2; ++c) {
      short8 bf = *(const short8*)(Wp + ((size_t)(t * NT + (w * 2 + c)) * 64 + lane) * 8);
      #pragma unroll
      for (int m = 0; m < MT; ++m)
        acc[m][c] = mfma16(a[m], bf, acc[m][c]);
    }
  }
  __builtin_amdgcn_s_setprio(0);
}

// ---- pack all weights -> bf16 MFMA B-fragments in ws ------------------------
__global__ __launch_bounds__(256) void k_pack(
    const float* __restrict__ W1w,  const float* __restrict__ W2w,
    const float* __restrict__ W3w,  const float* __restrict__ W11w,
    const float* __restrict__ W12w, const float* __restrict__ W13w,
    const float* __restrict__ Winw, const float* __restrict__ Woutw,
    unsigned short* __restrict__ dst)
{
  const int f = blockIdx.x * 256 + threadIdx.x;
  if (f >= 36864) return;
  const float* src; int row0 = 0, Ncols = 128, NT = 8, lf;
  if (f < 20480) {
    const int seg = f >> 11; lf = f & 2047;
    switch (seg) {
      case 0: src = W1w;  row0 = 0;   break;
      case 1: src = W1w;  row0 = 128; break;
      case 2: src = W1w;  row0 = 256; break;
      case 3: src = W2w;  break;
      case 4: src = W3w;  break;
      case 5: src = W11w; row0 = 0;   break;
      case 6: src = W11w; row0 = 128; break;
      case 7: src = W11w; row0 = 256; break;
      case 8: src = W12w; break;
      default: src = W13w; break;
    }
  } else if (f < 28672) { src = Winw; lf = f - 20480; NT = 32; Ncols = 512; }
  else { src = Woutw; lf = f - 28672; }
  const int l = lf & 63;
  const int g = lf >> 6;
  const int c = g % NT;
  const int t = g / NT;
  const int r0 = row0 + t * 32 + ((l >> 4) << 3);
  const int col = c * 16 + (l & 15);
  short8 vv;
  #pragma unroll
  for (int b = 0; b < 8; ++b)
    vv[b] = (short)f2bf(src[(size_t)(r0 + b) * Ncols + col]);
  *(short8*)(dst + (size_t)f * 8) = vv;
}

// ---- precompute P1 = X@Wtop + bias (f32), P3 = X@Wbot (bf16), X:[4096,128] --
__global__ __launch_bounds__(256) void k_pre(
    const float* __restrict__ X,
    const unsigned short* __restrict__ Wtp,
    const unsigned short* __restrict__ Wbp,
    const float* __restrict__ bias,
    float* __restrict__ P1, unsigned short* __restrict__ P3)
{
  __shared__ __align__(16) unsigned short Xs2[16 * 136];
  const int tid = threadIdx.x;
  const int lane = tid & 63;
  const int w = tid >> 6;
  const int rr = lane & 15;
  const int kg = (lane >> 4) << 3;
  const int row0 = blockIdx.x * 16;

  for (int e = tid; e < 512; e += 256) {
    const int r = e >> 5, q = (e & 31) << 2;
    float4 v = *(const float4*)(X + (size_t)(row0 + r) * 128 + q);
    uint2 pk; pk.x = pk2(v.x, v.y); pk.y = pk2(v.z, v.w);
    *(uint2*)(&Xs2[r * 136 + q]) = pk;
  }
  __syncthreads();

  const f32x4 zf = {0.f, 0.f, 0.f, 0.f};
  f32x4 a0[2] = {zf, zf}, a1[2] = {zf, zf};
  #pragma unroll
  for (int t = 0; t < 4; ++t) {
    const short8 a = *(const short8*)(&Xs2[rr * 136 + t * 32 + kg]);
    #pragma unroll
    for (int c = 0; c < 2; ++c) {
      short8 bt = *(const short8*)(Wtp + ((size_t)(t * 8 + (w * 2 + c)) * 64 + lane) * 8);
      a0[c] = mfma16(a, bt, a0[c]);
      short8 bb = *(const short8*)(Wbp + ((size_t)(t * 8 + (w * 2 + c)) * 64 + lane) * 8);
      a1[c] = mfma16(a, bb, a1[c]);
    }
  }
  #pragma unroll
  for (int c = 0; c < 2; ++c) {
    const int col = w * 32 + c * 16 + rr;
    const float b = bias[col];
    #pragma unroll
    for (int r = 0; r < 4; ++r) {
      const int row = row0 + ((lane >> 4) << 2) + r;
      P1[(size_t)row * 128 + col] = a0[c][r] + b;
      P3[(size_t)row * 128 + col] = f2bf(a1[c][r]);
    }
  }
}

// ---------------- node message pass + LN1 -> hVn1; side-writes hEb -----------
template<bool HEB>
__global__ __launch_bounds__(256) void k_node_t(
    const float* __restrict__ hV, const float* __restrict__ hE,
    unsigned short* __restrict__ hEbOut,
    const int* __restrict__ Eidx, const float* __restrict__ maskA,
    const float* __restrict__ P1g, const unsigned short* __restrict__ P3g,
    const unsigned short* __restrict__ Wmidp,
    const unsigned short* __restrict__ W2p, const float* __restrict__ W2b,
    const unsigned short* __restrict__ W3p, const float* __restrict__ W3b,
    const float* __restrict__ ln1g, const float* __restrict__ ln1b,
    float* __restrict__ hVn1)
{
  __shared__ __align__(16) unsigned short Xs[48 * 136];   // hE bf16, later GEMM2-out
  __shared__ __align__(16) unsigned short Ms[48 * 136];   // P3 gather, later GEMM1-out
  __shared__ float maskv[48];
  __shared__ float dhs[128];
  __shared__ float red[2];

  const int tid = threadIdx.x;
  const int lane = tid & 63;
  const int w = tid >> 6;
  const int rr = lane & 15;
  const int g4 = (lane >> 4) << 2;
  const int bidx = (blockIdx.x & 7) * 512 + (blockIdx.x >> 3);   // XCD swizzle
  const int bbase = bidx & ~2047;

  const float* hErow = hE + (size_t)bidx * 6144;
  const int* idxr = Eidx + (size_t)bidx * 48;

  if (tid < 48) maskv[tid] = maskA[(size_t)bidx * 48 + tid];

  for (int e = tid; e < 1536; e += 256) {                 // hE f32 -> bf16 LDS
    const int r = e >> 5, q = (e & 31) << 2;
    float4 v = *(const float4*)(hErow + r * 128 + q);
    uint2 pk; pk.x = pk2(v.x, v.y); pk.y = pk2(v.z, v.w);
    *(uint2*)(&Xs[r * 136 + q]) = pk;
    if constexpr (HEB)
      *(uint2*)(hEbOut + (size_t)bidx * 6144 + r * 128 + q) = pk;
  }
  for (int e = tid; e < 768; e += 256) {                  // gather P3 rows
    const int r = e >> 4, q = (e & 15) << 3;
    const int j = idxr[r];
    *(short8*)(&Ms[r * 136 + q]) = *(const short8*)(P3g + (size_t)(bbase + j) * 128 + q);
  }
  const float p1c0 = P1g[(size_t)bidx * 128 + w * 32 + rr];
  const float p1c1 = P1g[(size_t)bidx * 128 + w * 32 + 16 + rr];
  __syncthreads();                                        // B1

  // acc-init: P1 + gathered P3 (wave-own columns of Ms)
  f32x4 acc[3][2];
  #pragma unroll
  for (int m = 0; m < 3; ++m)
    #pragma unroll
    for (int c = 0; c < 2; ++c)
      #pragma unroll
      for (int r = 0; r < 4; ++r) {
        const int row = m * 16 + g4 + r;
        const int col = w * 32 + c * 16 + rr;
        acc[m][c][r] = (c ? p1c1 : p1c0) + bf2f(Ms[row * 136 + col]);
      }

  gemm_tiles<4, 3, 8>(Xs, 136, Wmidp, lane, w, acc);
  // gelu -> wave-own columns of Ms (same addrs this wave just read: race-free)
  #pragma unroll
  for (int m = 0; m < 3; ++m)
    #pragma unroll
    for (int c = 0; c < 2; ++c)
      #pragma unroll
      for (int r = 0; r < 4; ++r) {
        const int row = m * 16 + g4 + r;
        Ms[row * 136 + w * 32 + c * 16 + rr] = f2bf(gelu_f(acc[m][c][r]));
      }
  __syncthreads();                                        // B2

  const f32x4 zf = {0.f, 0.f, 0.f, 0.f};
  #pragma unroll
  for (int m = 0; m < 3; ++m) { acc[m][0] = zf; acc[m][1] = zf; }
  gemm_tiles<4, 3, 8>(Ms, 136, W2p, lane, w, acc);
  // gelu -> Xs (all GEMM1 reads of Xs completed before B2)
  {
    const float b0 = W2b[w * 32 + rr], b1 = W2b[w * 32 + 16 + rr];
    #pragma unroll
    for (int m = 0; m < 3; ++m)
      #pragma unroll
      for (int c = 0; c < 2; ++c)
        #pragma unroll
        for (int r = 0; r < 4; ++r) {
          const int row = m * 16 + g4 + r;
          Xs[row * 136 + w * 32 + c * 16 + rr] = f2bf(gelu_f(acc[m][c][r] + (c ? b1 : b0)));
        }
  }
  __syncthreads();                                        // B3

  #pragma unroll
  for (int m = 0; m < 3; ++m) { acc[m][0] = zf; acc[m][1] = zf; }
  gemm_tiles<4, 3, 8>(Xs, 136, W3p, lane, w, acc);

  {
    const float b0 = W3b[w * 32 + rr], b1 = W3b[w * 32 + 16 + rr];
    float p0 = 0.f, p1 = 0.f;
    #pragma unroll
    for (int m = 0; m < 3; ++m)
      #pragma unroll
      for (int r = 0; r < 4; ++r) {
        const float mk = maskv[m * 16 + g4 + r];
        p0 += mk * (acc[m][0][r] + b0);
        p1 += mk * (acc[m][1][r] + b1);
      }
    p0 += __shfl_xor(p0, 16); p0 += __shfl_xor(p0, 32);
    p1 += __shfl_xor(p1, 16); p1 += __shfl_xor(p1, 32);
    if (lane < 16) { dhs[w * 32 + lane] = p0; dhs[w * 32 + 16 + lane] = p1; }
  }
  __syncthreads();                                        // B4

  if (tid < 64) {
    const float x0 = hV[(size_t)bidx * 128 + tid]      + dhs[tid]      * (1.0f / 30.0f);
    const float x1 = hV[(size_t)bidx * 128 + 64 + tid] + dhs[tid + 64] * (1.0f / 30.0f);
    float s = x0 + x1, q2 = x0 * x0 + x1 * x1;
    #pragma unroll
    for (int msk = 1; msk < 64; msk <<= 1) {
      s += __shfl_xor(s, msk);
      q2 += __shfl_xor(q2, msk);
    }
    if (tid == 0) {
      const float mean = s * (1.f / 128.f);
      red[0] = mean;
      red[1] = rsqrtf(q2 * (1.f / 128.f) - mean * mean + 1e-5f);
    }
  }
  __syncthreads();                                        // B5
  if (tid < 128) {
    const float x = hV[(size_t)bidx * 128 + tid] + dhs[tid] * (1.0f / 30.0f);
    hVn1[(size_t)bidx * 128 + tid] = (x - red[0]) * red[1] * ln1g[tid] + ln1b[tid];
  }
}

// ---------------- FFN + LN2 + mask_V -> outV; fused P1/P3 for edge pass ------
__global__ __launch_bounds__(256) void k_ffn(
    const float* __restrict__ hVn1,
    const unsigned short* __restrict__ Winp, const float* __restrict__ Winb,
    const unsigned short* __restrict__ Woutp, const float* __restrict__ Woutb,
    const float* __restrict__ ln2g, const float* __restrict__ ln2b,
    const float* __restrict__ maskV,
    const unsigned short* __restrict__ W11tp, const unsigned short* __restrict__ W11bp,
    const float* __restrict__ W11b,
    float* __restrict__ outV, float* __restrict__ P1, unsigned short* __restrict__ P3)
{
  __shared__ __align__(16) unsigned short Xs2[16 * 136];
  __shared__ __align__(16) unsigned short Ys[16 * 520];
  __shared__ __align__(16) unsigned short Ts[16 * 136];
  __shared__ float Rs[16 * 128];

  const int tid = threadIdx.x;
  const int lane = tid & 63;
  const int w = tid >> 6;
  const int rr = lane & 15;
  const int kg = (lane >> 4) << 3;
  const int row0 = blockIdx.x * 16;

  for (int e = tid; e < 512; e += 256) {
    const int r = e >> 5, q = (e & 31) << 2;
    float4 v = *(const float4*)(hVn1 + (size_t)(row0 + r) * 128 + q);
    uint2 pk; pk.x = pk2(v.x, v.y); pk.y = pk2(v.z, v.w);
    *(uint2*)(&Xs2[r * 136 + q]) = pk;
  }
  __syncthreads();

  const f32x4 zf = {0.f, 0.f, 0.f, 0.f};
  f32x4 acc1[8];
  #pragma unroll
  for (int c = 0; c < 8; ++c) acc1[c] = zf;
  #pragma unroll
  for (int t = 0; t < 4; ++t) {
    const short8 a = *(const short8*)(&Xs2[rr * 136 + t * 32 + kg]);
    #pragma unroll
    for (int c = 0; c < 8; ++c) {
      const short8 bf = *(const short8*)(Winp + ((size_t)(t * 32 + w * 8 + c) * 64 + lane) * 8);
      acc1[c] = mfma16(a, bf, acc1[c]);
    }
  }
  #pragma unroll
  for (int c = 0; c < 8; ++c) {
    const int col = w * 128 + c * 16 + rr;
    const float bias = Winb[col];
    #pragma unroll
    for (int r = 0; r < 4; ++r) {
      const int row = ((lane >> 4) << 2) + r;
      Ys[row * 520 + col] = f2bf(gelu_f(acc1[c][r] + bias));
    }
  }
  __syncthreads();

  f32x4 acc2[2];
  acc2[0] = zf; acc2[1] = zf;
  #pragma unroll 4
  for (int t = 0; t < 16; ++t) {
    const short8 a = *(const short8*)(&Ys[rr * 520 + t * 32 + kg]);
    #pragma unroll
    for (int c = 0; c < 2; ++c) {
      const short8 bf = *(const short8*)(Woutp + ((size_t)(t * 8 + w * 2 + c) * 64 + lane) * 8);
      acc2[c] = mfma16(a, bf, acc2[c]);
    }
  }
  #pragma unroll
  for (int c = 0; c < 2; ++c) {
    const int col = w * 32 + c * 16 + rr;
    const float bias = Woutb[col];
    #pragma unroll
    for (int r = 0; r < 4; ++r) {
      const int row = ((lane >> 4) << 2) + r;
      Rs[row * 128 + col] = acc2[c][r] + bias + hVn1[(size_t)(row0 + row) * 128 + col];
    }
  }
  __syncthreads();

  const float g0 = ln2g[lane], g1 = ln2g[lane + 64];
  const float be0 = ln2b[lane], be1 = ln2b[lane + 64];
  for (int i = 0; i < 4; ++i) {
    const int row = w * 4 + i;
    const int grow = row0 + row;
    const float x0 = Rs[row * 128 + lane], x1 = Rs[row * 128 + 64 + lane];
    float s = x0 + x1, q2 = x0 * x0 + x1 * x1;
    #pragma unroll
    for (int msk = 1; msk < 64; msk <<= 1) {
      s += __shfl_xor(s, msk);
      q2 += __shfl_xor(q2, msk);
    }
    const float mean = s * (1.f / 128.f);
    const float rstd = rsqrtf(q2 * (1.f / 128.f) - mean * mean + 1e-5f);
    const float mv = maskV[grow];
    const float y0 = ((x0 - mean) * rstd * g0 + be0) * mv;
    const float y1 = ((x1 - mean) * rstd * g1 + be1) * mv;
    outV[(size_t)grow * 128 + lane]      = y0;
    outV[(size_t)grow * 128 + 64 + lane] = y1;
    Ts[row * 136 + lane]      = f2bf(y0);
    Ts[row * 136 + 64 + lane] = f2bf(y1);
  }
  __syncthreads();

  // fused k_pre for the edge pass: P1 = outV@W11top + b, P3 = outV@W11bot
  f32x4 a0[2] = {zf, zf}, a1[2] = {zf, zf};
  #pragma unroll
  for (int t = 0; t < 4; ++t) {
    const short8 a = *(const short8*)(&Ts[rr * 136 + t * 32 + kg]);
    #pragma unroll
    for (int c = 0; c < 2; ++c) {
      short8 bt = *(const short8*)(W11tp + ((size_t)(t * 8 + (w * 2 + c)) * 64 + lane) * 8);
      a0[c] = mfma16(a, bt, a0[c]);
      short8 bb = *(const short8*)(W11bp + ((size_t)(t * 8 + (w * 2 + c)) * 64 + lane) * 8);
      a1[c] = mfma16(a, bb, a1[c]);
    }
  }
  #pragma unroll
  for (int c = 0; c < 2; ++c) {
    const int col = w * 32 + c * 16 + rr;
    const float b = W11b[col];
    #pragma unroll
    for (int r = 0; r < 4; ++r) {
      const int row = row0 + ((lane >> 4) << 2) + r;
      P1[(size_t)row * 128 + col] = a0[c][r] + b;
      P3[(size_t)row * 128 + col] = f2bf(a1[c][r]);
    }
  }
}

// ---------------- edge update + LN3 -> outE ----------------------------------
template<bool HEB>
__global__ __launch_bounds__(256) void k_edge_t(
    const float* __restrict__ hE, const unsigned short* __restrict__ hEb,
    const int* __restrict__ Eidx,
    const float* __restrict__ P1g, const unsigned short* __restrict__ P3g,
    const unsigned short* __restrict__ Wmidp,
    const unsigned short* __restrict__ W12p, const float* __restrict__ W12b,
    const unsigned short* __restrict__ W13p, const float* __restrict__ W13b,
    const float* __restrict__ ln3g, const float* __restrict__ ln3b,
    float* __restrict__ outE)
{
  __shared__ __align__(16) unsigned short Xs[48 * 136];   // hE bf16, later GEMM2-out
  __shared__ __align__(16) unsigned short Ms[48 * 136];   // P3 gather, later GEMM1-out
  __shared__ float sums[48 * 4];
  __shared__ float sqs[48 * 4];
  __shared__ float mr[96];

  const int tid = threadIdx.x;
  const int lane = tid & 63;
  const int w = tid >> 6;
  const int rr = lane & 15;
  const int g4 = (lane >> 4) << 2;
  const int bidx = (blockIdx.x & 7) * 512 + (blockIdx.x >> 3);   // XCD swizzle
  const int bbase = bidx & ~2047;

  const int* idxr = Eidx + (size_t)bidx * 48;

  if constexpr (HEB) {
    for (int e = tid; e < 768; e += 256) {               // bf16 staging (cheap)
      const int r = e >> 4, q = (e & 15) << 3;
      *(short8*)(&Xs[r * 136 + q]) = *(const short8*)(hEb + (size_t)bidx * 6144 + r * 128 + q);
    }
  } else {
    const float* hErow = hE + (size_t)bidx * 6144;
    for (int e = tid; e < 1536; e += 256) {
      const int r = e >> 5, q = (e & 31) << 2;
      float4 v = *(const float4*)(hErow + r * 128 + q);
      uint2 pk; pk.x = pk2(v.x, v.y); pk.y = pk2(v.z, v.w);
      *(uint2*)(&Xs[r * 136 + q]) = pk;
    }
  }
  for (int e = tid; e < 768; e += 256) {
    const int r = e >> 4, q = (e & 15) << 3;
    const int j = idxr[r];
    *(short8*)(&Ms[r * 136 + q]) = *(const short8*)(P3g + (size_t)(bbase + j) * 128 + q);
  }
  const float p1c0 = P1g[(size_t)bidx * 128 + w * 32 + rr];
  const float p1c1 = P1g[(size_t)bidx * 128 + w * 32 + 16 + rr];
  __syncthreads();                                        // B1

  // residual capture (wave-own cols) + acc-init
  f32x4 acc[3][2];
  float res[3][2][4];
  #pragma unroll
  for (int m = 0; m < 3; ++m)
    #pragma unroll
    for (int c = 0; c < 2; ++c)
      #pragma unroll
      for (int r = 0; r < 4; ++r) {
        const int row = m * 16 + g4 + r;
        const int col = w * 32 + c * 16 + rr;
        acc[m][c][r] = (c ? p1c1 : p1c0) + bf2f(Ms[row * 136 + col]);
        res[m][c][r] = bf2f(Xs[row * 136 + col]);
      }

  gemm_tiles<4, 3, 8>(Xs, 136, Wmidp, lane, w, acc);
  #pragma unroll
  for (int m = 0; m < 3; ++m)
    #pragma unroll
    for (int c = 0; c < 2; ++c)
      #pragma unroll
      for (int r = 0; r < 4; ++r) {
        const int row = m * 16 + g4 + r;
        Ms[row * 136 + w * 32 + c * 16 + rr] = f2bf(gelu_f(acc[m][c][r]));
      }
  __syncthreads();                                        // B2

  const f32x4 zf = {0.f, 0.f, 0.f, 0.f};
  #pragma unroll
  for (int m = 0; m < 3; ++m) { acc[m][0] = zf; acc[m][1] = zf; }
  gemm_tiles<4, 3, 8>(Ms, 136, W12p, lane, w, acc);
  {
    const float b0 = W12b[w * 32 + rr], b1 = W12b[w * 32 + 16 + rr];
    #pragma unroll
    for (int m = 0; m < 3; ++m)
      #pragma unroll
      for (int c = 0; c < 2; ++c)
        #pragma unroll
        for (int r = 0; r < 4; ++r) {
          const int row = m * 16 + g4 + r;
          Xs[row * 136 + w * 32 + c * 16 + rr] = f2bf(gelu_f(acc[m][c][r] + (c ? b1 : b0)));
        }
  }
  __syncthreads();                                        // B3

  #pragma unroll
  for (int m = 0; m < 3; ++m) { acc[m][0] = zf; acc[m][1] = zf; }
  gemm_tiles<4, 3, 8>(Xs, 136, W13p, lane, w, acc);

  {
    const float b0 = W13b[w * 32 + rr], b1 = W13b[w * 32 + 16 + rr];
    #pragma unroll
    for (int m = 0; m < 3; ++m)
      #pragma unroll
      for (int r = 0; r < 4; ++r) {
        const int row = m * 16 + g4 + r;
        acc[m][0][r] += b0 + res[m][0][r];
        acc[m][1][r] += b1 + res[m][1][r];
        float s = acc[m][0][r] + acc[m][1][r];
        float q2 = acc[m][0][r] * acc[m][0][r] + acc[m][1][r] * acc[m][1][r];
        s += __shfl_xor(s, 1); q2 += __shfl_xor(q2, 1);
        s += __shfl_xor(s, 2); q2 += __shfl_xor(q2, 2);
        s += __shfl_xor(s, 4); q2 += __shfl_xor(q2, 4);
        s += __shfl_xor(s, 8); q2 += __shfl_xor(q2, 8);
        if ((lane & 15) == 0) { sums[row * 4 + w] = s; sqs[row * 4 + w] = q2; }
      }
  }
  __syncthreads();                                        // B4
  if (tid < 48) {
    const float s = sums[tid * 4] + sums[tid * 4 + 1] + sums[tid * 4 + 2] + sums[tid * 4 + 3];
    const float q2 = sqs[tid * 4] + sqs[tid * 4 + 1] + sqs[tid * 4 + 2] + sqs[tid * 4 + 3];
    const float mean = s * (1.f / 128.f);
    mr[tid * 2] = mean;
    mr[tid * 2 + 1] = rsqrtf(q2 * (1.f / 128.f) - mean * mean + 1e-5f);
  }
  __syncthreads();                                        // B5
  {
    const float g0 = ln3g[w * 32 + rr], g1 = ln3g[w * 32 + 16 + rr];
    const float be0 = ln3b[w * 32 + rr], be1 = ln3b[w * 32 + 16 + rr];
    #pragma unroll
    for (int m = 0; m < 3; ++m)
      #pragma unroll
      for (int r = 0; r < 4; ++r) {
        const int row = m * 16 + g4 + r;
        const float mean = mr[row * 2], rstd = mr[row * 2 + 1];
        const size_t base = (size_t)bidx * 6144 + (size_t)row * 128 + w * 32 + rr;
        outE[base]      = (acc[m][0][r] - mean) * rstd * g0 + be0;
        outE[base + 16] = (acc[m][1][r] - mean) * rstd * g1 + be1;
      }
  }
}

extern "C" void kernel_launch(void* const* d_in, const int* in_sizes, int n_in,
                              void* d_out, int out_size, void* d_ws, size_t ws_size,
                              hipStream_t stream) {
  const float* hV    = (const float*)d_in[0];
  const float* hE    = (const float*)d_in[1];
  const int*   Eidx  = (const int*)d_in[2];
  const float* maskV = (const float*)d_in[3];
  const float* maskA = (const float*)d_in[4];
  const float* W1w  = (const float*)d_in[5];  const float* W1b  = (const float*)d_in[6];
  const float* W2w  = (const float*)d_in[7];  const float* W2b  = (const float*)d_in[8];
  const float* W3w  = (const float*)d_in[9];  const float* W3b  = (const float*)d_in[10];
  const float* W11w = (const float*)d_in[11]; const float* W11b = (const float*)d_in[12];
  const float* W12w = (const float*)d_in[13]; const float* W12b = (const float*)d_in[14];
  const float* W13w = (const float*)d_in[15]; const float* W13b = (const float*)d_in[16];
  const float* Winw = (const float*)d_in[17]; const float* Winb = (const float*)d_in[18];
  const float* Woutw= (const float*)d_in[19]; const float* Woutb= (const float*)d_in[20];
  const float* ln1g = (const float*)d_in[21]; const float* ln1b = (const float*)d_in[22];
  const float* ln2g = (const float*)d_in[23]; const float* ln2b = (const float*)d_in[24];
  const float* ln3g = (const float*)d_in[25]; const float* ln3b = (const float*)d_in[26];

  float* outV = (float*)d_out;                       // [4096,128]
  float* outE = outV + (size_t)4096 * 128;           // [4096*48,128]

  char* ws = (char*)d_ws;
  float* hVn1 = (float*)ws;                                  // 2 MB
  float* P1   = (float*)(ws + (size_t)2 * 1024 * 1024);      // 2 MB
  unsigned short* P3 = (unsigned short*)(ws + (size_t)4 * 1024 * 1024);  // 1 MB
  unsigned short* Wp = (unsigned short*)(ws + (size_t)5 * 1024 * 1024);  // 576 KB
  unsigned short* hEb = (unsigned short*)(ws + (size_t)6 * 1024 * 1024); // 48 MB bf16

  const size_t NEED = (size_t)6 * 1024 * 1024 + (size_t)4096 * 48 * 128 * 2;
  const bool heb = ws_size >= NEED;

  const unsigned short* W1top_p  = Wp;
  const unsigned short* W1mid_p  = Wp + (size_t)2048 * 8;
  const unsigned short* W1bot_p  = Wp + (size_t)4096 * 8;
  const unsigned short* W2p      = Wp + (size_t)6144 * 8;
  const unsigned short* W3p      = Wp + (size_t)8192 * 8;
  const unsigned short* W11top_p = Wp + (size_t)10240 * 8;
  const unsigned short* W11mid_p = Wp + (size_t)12288 * 8;
  const unsigned short* W11bot_p = Wp + (size_t)14336 * 8;
  const unsigned short* W12p     = Wp + (size_t)16384 * 8;
  const unsigned short* W13p     = Wp + (size_t)18432 * 8;
  const unsigned short* Winp     = Wp + (size_t)20480 * 8;
  const unsigned short* Woutp    = Wp + (size_t)28672 * 8;

  k_pack<<<144, 256, 0, stream>>>(W1w, W2w, W3w, W11w, W12w, W13w, Winw, Woutw, Wp);
  k_pre<<<256, 256, 0, stream>>>(hV, W1top_p, W1bot_p, W1b, P1, P3);

  if (heb)
    k_node_t<true><<<4096, 256, 0, stream>>>(hV, hE, hEb, Eidx, maskA, P1, P3,
                                             W1mid_p, W2p, W2b, W3p, W3b,
                                             ln1g, ln1b, hVn1);
  else
    k_node_t<false><<<4096, 256, 0, stream>>>(hV, hE, hEb, Eidx, maskA, P1, P3,
                                              W1mid_p, W2p, W2b, W3p, W3b,
                                              ln1g, ln1b, hVn1);

  k_ffn<<<256, 256, 0, stream>>>(hVn1, Winp, Winb, Woutp, Woutb,
                                 ln2g, ln2b, maskV,
                                 W11top_p, W11bot_p, W11b,
                                 outV, P1, P3);

  if (heb)
    k_edge_t<true><<<4096, 256, 0, stream>>>(hE, hEb, Eidx, P1, P3,
                                             W11mid_p, W12p, W12b, W13p, W13b,
                                             ln3g, ln3b, outE);
  else
    k_edge_t<false><<<4096, 256, 0, stream>>>(hE, hEb, Eidx, P1, P3,
                                              W11mid_p, W12p, W12b, W13p, W13b,
                                              ln3g, ln3b, outE);
}

// Round 12
// 137.908 us; speedup vs baseline: 1.2170x; 1.0141x over previous
//
#include <hip/hip_runtime.h>
#include <hip/hip_bf16.h>

#define DEVINL __device__ __forceinline__

typedef __attribute__((ext_vector_type(8))) short short8;
typedef __attribute__((ext_vector_type(4))) float f32x4;

DEVINL unsigned short f2bf(float x) {
  __hip_bfloat16 h = __float2bfloat16(x);
  return __builtin_bit_cast(unsigned short, h);
}
DEVINL unsigned int pk2(float lo, float hi) {
  return (unsigned int)f2bf(lo) | ((unsigned int)f2bf(hi) << 16);
}
DEVINL float bf2f(unsigned short h) {
  union { unsigned int u; float f; } c; c.u = ((unsigned int)h) << 16;
  return c.f;
}
// tanh-form GELU (branchless): |diff vs erf-GELU| <~3e-3, far under threshold.
DEVINL float gelu_f(float x) {
  const float u = x * x;
  const float y = x * (0.7978845608f + 0.0356774081f * u);
  const float e = __expf(-2.0f * y);
  return x * __builtin_amdgcn_rcpf(1.0f + e);
}
DEVINL f32x4 mfma16(short8 a, short8 b, f32x4 c) {
  return __builtin_amdgcn_mfma_f32_16x16x32_bf16(a, b, c, 0, 0, 0);
}

// GEMM from LDS A-tile (row-major, ldx bf16 elems) with pre-packed B frags.
template<int KSTEPS, int MT, int NT>
DEVINL void gemm_tiles(const unsigned short* Xl, int ldx,
                       const unsigned short* __restrict__ Wp,
                       int lane, int w, f32x4 (&acc)[MT][2])
{
  const int rr = lane & 15;
  const int kg = (lane >> 4) << 3;
  __builtin_amdgcn_s_setprio(1);
  #pragma unroll
  for (int t = 0; t < KSTEPS; ++t) {
    short8 a[MT];
    #pragma unroll
    for (int m = 0; m < MT; ++m)
      a[m] = *(const short8*)(Xl + (m * 16 + rr) * ldx + t * 32 + kg);
    #pragma unroll
    for (int c = 0; c < 2; ++c) {
      short8 bf = *(const short8*)(Wp + ((size_t)(t * NT + (w * 2 + c)) * 64 + lane) * 8);
      #pragma unroll
      for (int m = 0; m < MT; ++m)
        acc[m][c] = mfma16(a[m], bf, acc[m][c]);
    }
  }
  __builtin_amdgcn_s_setprio(0);
}

// ---- pack all weights -> bf16 MFMA B-fragments in ws ------------------------
__global__ __launch_bounds__(256) void k_pack(
    const float* __restrict__ W1w,  const float* __restrict__ W2w,
    const float* __restrict__ W3w,  const float* __restrict__ W11w,
    const float* __restrict__ W12w, const float* __restrict__ W13w,
    const float* __restrict__ Winw, const float* __restrict__ Woutw,
    unsigned short* __restrict__ dst)
{
  const int f = blockIdx.x * 256 + threadIdx.x;
  if (f >= 36864) return;
  const float* src; int row0 = 0, Ncols = 128, NT = 8, lf;
  if (f < 20480) {
    const int seg = f >> 11; lf = f & 2047;
    switch (seg) {
      case 0: src = W1w;  row0 = 0;   break;
      case 1: src = W1w;  row0 = 128; break;
      case 2: src = W1w;  row0 = 256; break;
      case 3: src = W2w;  break;
      case 4: src = W3w;  break;
      case 5: src = W11w; row0 = 0;   break;
      case 6: src = W11w; row0 = 128; break;
      case 7: src = W11w; row0 = 256; break;
      case 8: src = W12w; break;
      default: src = W13w; break;
    }
  } else if (f < 28672) { src = Winw; lf = f - 20480; NT = 32; Ncols = 512; }
  else { src = Woutw; lf = f - 28672; }
  const int l = lf & 63;
  const int g = lf >> 6;
  const int c = g % NT;
  const int t = g / NT;
  const int r0 = row0 + t * 32 + ((l >> 4) << 3);
  const int col = c * 16 + (l & 15);
  short8 vv;
  #pragma unroll
  for (int b = 0; b < 8; ++b)
    vv[b] = (short)f2bf(src[(size_t)(r0 + b) * Ncols + col]);
  *(short8*)(dst + (size_t)f * 8) = vv;
}

// ---- precompute P1 = X@Wtop + bias (f32), P3 = X@Wbot (bf16), X:[4096,128] --
__global__ __launch_bounds__(256) void k_pre(
    const float* __restrict__ X,
    const unsigned short* __restrict__ Wtp,
    const unsigned short* __restrict__ Wbp,
    const float* __restrict__ bias,
    float* __restrict__ P1, unsigned short* __restrict__ P3)
{
  __shared__ __align__(16) unsigned short Xs2[16 * 136];
  const int tid = threadIdx.x;
  const int lane = tid & 63;
  const int w = tid >> 6;
  const int rr = lane & 15;
  const int kg = (lane >> 4) << 3;
  const int row0 = blockIdx.x * 16;

  for (int e = tid; e < 512; e += 256) {
    const int r = e >> 5, q = (e & 31) << 2;
    float4 v = *(const float4*)(X + (size_t)(row0 + r) * 128 + q);
    uint2 pk; pk.x = pk2(v.x, v.y); pk.y = pk2(v.z, v.w);
    *(uint2*)(&Xs2[r * 136 + q]) = pk;
  }
  __syncthreads();

  const f32x4 zf = {0.f, 0.f, 0.f, 0.f};
  f32x4 a0[2] = {zf, zf}, a1[2] = {zf, zf};
  #pragma unroll
  for (int t = 0; t < 4; ++t) {
    const short8 a = *(const short8*)(&Xs2[rr * 136 + t * 32 + kg]);
    #pragma unroll
    for (int c = 0; c < 2; ++c) {
      short8 bt = *(const short8*)(Wtp + ((size_t)(t * 8 + (w * 2 + c)) * 64 + lane) * 8);
      a0[c] = mfma16(a, bt, a0[c]);
      short8 bb = *(const short8*)(Wbp + ((size_t)(t * 8 + (w * 2 + c)) * 64 + lane) * 8);
      a1[c] = mfma16(a, bb, a1[c]);
    }
  }
  #pragma unroll
  for (int c = 0; c < 2; ++c) {
    const int col = w * 32 + c * 16 + rr;
    const float b = bias[col];
    #pragma unroll
    for (int r = 0; r < 4; ++r) {
      const int row = row0 + ((lane >> 4) << 2) + r;
      P1[(size_t)row * 128 + col] = a0[c][r] + b;
      P3[(size_t)row * 128 + col] = f2bf(a1[c][r]);
    }
  }
}

// ---------------- node message pass + LN1 -> hVn1; side-writes hEb -----------
// GEMM3 collapsed: dh = (sum_k mask[k]*gelu(G2)[k,:]) @ W3 + (sum mask)*b3
template<bool HEB>
__global__ __launch_bounds__(256) void k_node_t(
    const float* __restrict__ hV, const float* __restrict__ hE,
    unsigned short* __restrict__ hEbOut,
    const int* __restrict__ Eidx, const float* __restrict__ maskA,
    const float* __restrict__ P1g, const unsigned short* __restrict__ P3g,
    const unsigned short* __restrict__ Wmidp,
    const unsigned short* __restrict__ W2p, const float* __restrict__ W2b,
    const float* __restrict__ W3w, const float* __restrict__ W3b,
    const float* __restrict__ ln1g, const float* __restrict__ ln1b,
    float* __restrict__ hVn1)
{
  __shared__ __align__(16) unsigned short Xs[48 * 136];   // hE bf16 (GEMM1 A)
  __shared__ __align__(16) unsigned short Ms[48 * 136];   // P3 gather, later G1-out
  __shared__ float maskv[48];
  __shared__ float dhs[128];      // s = masked colsum of gelu(G2)
  __shared__ float mv[256];       // matvec split-k partials
  __shared__ float red[1];        // sum(mask)

  const int tid = threadIdx.x;
  const int lane = tid & 63;
  const int w = tid >> 6;
  const int rr = lane & 15;
  const int g4 = (lane >> 4) << 2;
  const int bidx = (blockIdx.x & 7) * 512 + (blockIdx.x >> 3);   // XCD swizzle
  const int bbase = bidx & ~2047;

  const float* hErow = hE + (size_t)bidx * 6144;
  const int* idxr = Eidx + (size_t)bidx * 48;

  if (tid < 48) maskv[tid] = maskA[(size_t)bidx * 48 + tid];

  for (int e = tid; e < 1536; e += 256) {                 // hE f32 -> bf16 LDS
    const int r = e >> 5, q = (e & 31) << 2;
    float4 v = *(const float4*)(hErow + r * 128 + q);
    uint2 pk; pk.x = pk2(v.x, v.y); pk.y = pk2(v.z, v.w);
    *(uint2*)(&Xs[r * 136 + q]) = pk;
    if constexpr (HEB)
      *(uint2*)(hEbOut + (size_t)bidx * 6144 + r * 128 + q) = pk;
  }
  for (int e = tid; e < 768; e += 256) {                  // gather P3 rows
    const int r = e >> 4, q = (e & 15) << 3;
    const int j = idxr[r];
    *(short8*)(&Ms[r * 136 + q]) = *(const short8*)(P3g + (size_t)(bbase + j) * 128 + q);
  }
  const float p1c0 = P1g[(size_t)bidx * 128 + w * 32 + rr];
  const float p1c1 = P1g[(size_t)bidx * 128 + w * 32 + 16 + rr];
  __syncthreads();                                        // B1

  if (tid == 0) {                                         // sum(mask), tiny
    float nm = 0.f;
    for (int i = 0; i < 48; ++i) nm += maskv[i];
    red[0] = nm;
  }

  // acc-init: P1 + gathered P3 (wave-own columns of Ms)
  f32x4 acc[3][2];
  #pragma unroll
  for (int m = 0; m < 3; ++m)
    #pragma unroll
    for (int c = 0; c < 2; ++c)
      #pragma unroll
      for (int r = 0; r < 4; ++r) {
        const int row = m * 16 + g4 + r;
        const int col = w * 32 + c * 16 + rr;
        acc[m][c][r] = (c ? p1c1 : p1c0) + bf2f(Ms[row * 136 + col]);
      }

  gemm_tiles<4, 3, 8>(Xs, 136, Wmidp, lane, w, acc);
  // gelu -> wave-own columns of Ms (same addrs this wave just read: race-free)
  #pragma unroll
  for (int m = 0; m < 3; ++m)
    #pragma unroll
    for (int c = 0; c < 2; ++c)
      #pragma unroll
      for (int r = 0; r < 4; ++r) {
        const int row = m * 16 + g4 + r;
        Ms[row * 136 + w * 32 + c * 16 + rr] = f2bf(gelu_f(acc[m][c][r]));
      }
  __syncthreads();                                        // B2

  // GEMM2 (bias in C-init); gelu + masked colsum fully in-register
  {
    const float b0 = W2b[w * 32 + rr], b1 = W2b[w * 32 + 16 + rr];
    #pragma unroll
    for (int m = 0; m < 3; ++m) {
      acc[m][0] = (f32x4){b0, b0, b0, b0};
      acc[m][1] = (f32x4){b1, b1, b1, b1};
    }
  }
  gemm_tiles<4, 3, 8>(Ms, 136, W2p, lane, w, acc);
  {
    float p0 = 0.f, p1 = 0.f;
    #pragma unroll
    for (int m = 0; m < 3; ++m)
      #pragma unroll
      for (int r = 0; r < 4; ++r) {
        const float mk = maskv[m * 16 + g4 + r];
        p0 += mk * gelu_f(acc[m][0][r]);
        p1 += mk * gelu_f(acc[m][1][r]);
      }
    p0 += __shfl_xor(p0, 16); p0 += __shfl_xor(p0, 32);
    p1 += __shfl_xor(p1, 16); p1 += __shfl_xor(p1, 32);
    if (lane < 16) { dhs[w * 32 + lane] = p0; dhs[w * 32 + 16 + lane] = p1; }
  }
  __syncthreads();                                        // B3

  // matvec dh = s @ W3 (split-k over 2 halves, 256 threads, W3 L2-hot f32)
  {
    const int col = tid & 127;
    const int k0 = (tid >> 7) * 64;
    float part = 0.f;
    #pragma unroll 8
    for (int k = 0; k < 64; ++k)
      part = fmaf(dhs[k0 + k], W3w[(size_t)(k0 + k) * 128 + col], part);
    mv[tid] = part;
  }
  __syncthreads();                                        // B4

  if (w == 0) {                                           // wave 0 finishes LN1
    const float nm = red[0];
    const float dh0 = mv[lane]      + mv[128 + lane]      + nm * W3b[lane];
    const float dh1 = mv[64 + lane] + mv[192 + lane]      + nm * W3b[64 + lane];
    const float x0 = hV[(size_t)bidx * 128 + lane]      + dh0 * (1.0f / 30.0f);
    const float x1 = hV[(size_t)bidx * 128 + 64 + lane] + dh1 * (1.0f / 30.0f);
    float s = x0 + x1, sq = x0 * x0 + x1 * x1;
    #pragma unroll
    for (int msk = 1; msk < 64; msk <<= 1) {
      s += __shfl_xor(s, msk);
      sq += __shfl_xor(sq, msk);
    }
    const float mean = s * (1.f / 128.f);
    const float rstd = rsqrtf(sq * (1.f / 128.f) - mean * mean + 1e-5f);
    hVn1[(size_t)bidx * 128 + lane]      = (x0 - mean) * rstd * ln1g[lane] + ln1b[lane];
    hVn1[(size_t)bidx * 128 + 64 + lane] = (x1 - mean) * rstd * ln1g[64 + lane] + ln1b[64 + lane];
  }
}

// ---------------- FFN + LN2 + mask_V -> outV; fused P1/P3 for edge pass ------
__global__ __launch_bounds__(256) void k_ffn(
    const float* __restrict__ hVn1,
    const unsigned short* __restrict__ Winp, const float* __restrict__ Winb,
    const unsigned short* __restrict__ Woutp, const float* __restrict__ Woutb,
    const float* __restrict__ ln2g, const float* __restrict__ ln2b,
    const float* __restrict__ maskV,
    const unsigned short* __restrict__ W11tp, const unsigned short* __restrict__ W11bp,
    const float* __restrict__ W11b,
    float* __restrict__ outV, float* __restrict__ P1, unsigned short* __restrict__ P3)
{
  __shared__ __align__(16) unsigned short Xs2[16 * 136];
  __shared__ __align__(16) unsigned short Ys[16 * 520];
  __shared__ __align__(16) unsigned short Ts[16 * 136];
  __shared__ float Rs[16 * 128];

  const int tid = threadIdx.x;
  const int lane = tid & 63;
  const int w = tid >> 6;
  const int rr = lane & 15;
  const int kg = (lane >> 4) << 3;
  const int row0 = blockIdx.x * 16;

  for (int e = tid; e < 512; e += 256) {
    const int r = e >> 5, q = (e & 31) << 2;
    float4 v = *(const float4*)(hVn1 + (size_t)(row0 + r) * 128 + q);
    uint2 pk; pk.x = pk2(v.x, v.y); pk.y = pk2(v.z, v.w);
    *(uint2*)(&Xs2[r * 136 + q]) = pk;
  }
  __syncthreads();

  const f32x4 zf = {0.f, 0.f, 0.f, 0.f};
  f32x4 acc1[8];
  #pragma unroll
  for (int c = 0; c < 8; ++c) acc1[c] = zf;
  #pragma unroll
  for (int t = 0; t < 4; ++t) {
    const short8 a = *(const short8*)(&Xs2[rr * 136 + t * 32 + kg]);
    #pragma unroll
    for (int c = 0; c < 8; ++c) {
      const short8 bf = *(const short8*)(Winp + ((size_t)(t * 32 + w * 8 + c) * 64 + lane) * 8);
      acc1[c] = mfma16(a, bf, acc1[c]);
    }
  }
  #pragma unroll
  for (int c = 0; c < 8; ++c) {
    const int col = w * 128 + c * 16 + rr;
    const float bias = Winb[col];
    #pragma unroll
    for (int r = 0; r < 4; ++r) {
      const int row = ((lane >> 4) << 2) + r;
      Ys[row * 520 + col] = f2bf(gelu_f(acc1[c][r] + bias));
    }
  }
  __syncthreads();

  f32x4 acc2[2];
  acc2[0] = zf; acc2[1] = zf;
  #pragma unroll 4
  for (int t = 0; t < 16; ++t) {
    const short8 a = *(const short8*)(&Ys[rr * 520 + t * 32 + kg]);
    #pragma unroll
    for (int c = 0; c < 2; ++c) {
      const short8 bf = *(const short8*)(Woutp + ((size_t)(t * 8 + w * 2 + c) * 64 + lane) * 8);
      acc2[c] = mfma16(a, bf, acc2[c]);
    }
  }
  #pragma unroll
  for (int c = 0; c < 2; ++c) {
    const int col = w * 32 + c * 16 + rr;
    const float bias = Woutb[col];
    #pragma unroll
    for (int r = 0; r < 4; ++r) {
      const int row = ((lane >> 4) << 2) + r;
      Rs[row * 128 + col] = acc2[c][r] + bias + hVn1[(size_t)(row0 + row) * 128 + col];
    }
  }
  __syncthreads();

  const float g0 = ln2g[lane], g1 = ln2g[lane + 64];
  const float be0 = ln2b[lane], be1 = ln2b[lane + 64];
  for (int i = 0; i < 4; ++i) {
    const int row = w * 4 + i;
    const int grow = row0 + row;
    const float x0 = Rs[row * 128 + lane], x1 = Rs[row * 128 + 64 + lane];
    float s = x0 + x1, q2 = x0 * x0 + x1 * x1;
    #pragma unroll
    for (int msk = 1; msk < 64; msk <<= 1) {
      s += __shfl_xor(s, msk);
      q2 += __shfl_xor(q2, msk);
    }
    const float mean = s * (1.f / 128.f);
    const float rstd = rsqrtf(q2 * (1.f / 128.f) - mean * mean + 1e-5f);
    const float mv = maskV[grow];
    const float y0 = ((x0 - mean) * rstd * g0 + be0) * mv;
    const float y1 = ((x1 - mean) * rstd * g1 + be1) * mv;
    outV[(size_t)grow * 128 + lane]      = y0;
    outV[(size_t)grow * 128 + 64 + lane] = y1;
    Ts[row * 136 + lane]      = f2bf(y0);
    Ts[row * 136 + 64 + lane] = f2bf(y1);
  }
  __syncthreads();

  // fused k_pre for the edge pass: P1 = outV@W11top + b, P3 = outV@W11bot
  f32x4 a0[2] = {zf, zf}, a1[2] = {zf, zf};
  #pragma unroll
  for (int t = 0; t < 4; ++t) {
    const short8 a = *(const short8*)(&Ts[rr * 136 + t * 32 + kg]);
    #pragma unroll
    for (int c = 0; c < 2; ++c) {
      short8 bt = *(const short8*)(W11tp + ((size_t)(t * 8 + (w * 2 + c)) * 64 + lane) * 8);
      a0[c] = mfma16(a, bt, a0[c]);
      short8 bb = *(const short8*)(W11bp + ((size_t)(t * 8 + (w * 2 + c)) * 64 + lane) * 8);
      a1[c] = mfma16(a, bb, a1[c]);
    }
  }
  #pragma unroll
  for (int c = 0; c < 2; ++c) {
    const int col = w * 32 + c * 16 + rr;
    const float b = W11b[col];
    #pragma unroll
    for (int r = 0; r < 4; ++r) {
      const int row = row0 + ((lane >> 4) << 2) + r;
      P1[(size_t)row * 128 + col] = a0[c][r] + b;
      P3[(size_t)row * 128 + col] = f2bf(a1[c][r]);
    }
  }
}

// ---------------- edge update + LN3 -> outE ----------------------------------
template<bool HEB>
__global__ __launch_bounds__(256) void k_edge_t(
    const float* __restrict__ hE, const unsigned short* __restrict__ hEb,
    const int* __restrict__ Eidx,
    const float* __restrict__ P1g, const unsigned short* __restrict__ P3g,
    const unsigned short* __restrict__ Wmidp,
    const unsigned short* __restrict__ W12p, const float* __restrict__ W12b,
    const unsigned short* __restrict__ W13p, const float* __restrict__ W13b,
    const float* __restrict__ ln3g, const float* __restrict__ ln3b,
    float* __restrict__ outE)
{
  __shared__ __align__(16) unsigned short Xs[48 * 136];   // hE bf16, later GEMM2-out
  __shared__ __align__(16) unsigned short Ms[48 * 136];   // P3 gather, later GEMM1-out
  __shared__ float sums[48 * 4];
  __shared__ float sqs[48 * 4];
  __shared__ float mr[96];

  const int tid = threadIdx.x;
  const int lane = tid & 63;
  const int w = tid >> 6;
  const int rr = lane & 15;
  const int g4 = (lane >> 4) << 2;
  const int bidx = (blockIdx.x & 7) * 512 + (blockIdx.x >> 3);   // XCD swizzle
  const int bbase = bidx & ~2047;

  const int* idxr = Eidx + (size_t)bidx * 48;

  if constexpr (HEB) {
    for (int e = tid; e < 768; e += 256) {               // bf16 staging (cheap)
      const int r = e >> 4, q = (e & 15) << 3;
      *(short8*)(&Xs[r * 136 + q]) = *(const short8*)(hEb + (size_t)bidx * 6144 + r * 128 + q);
    }
  } else {
    const float* hErow = hE + (size_t)bidx * 6144;
    for (int e = tid; e < 1536; e += 256) {
      const int r = e >> 5, q = (e & 31) << 2;
      float4 v = *(const float4*)(hErow + r * 128 + q);
      uint2 pk; pk.x = pk2(v.x, v.y); pk.y = pk2(v.z, v.w);
      *(uint2*)(&Xs[r * 136 + q]) = pk;
    }
  }
  for (int e = tid; e < 768; e += 256) {
    const int r = e >> 4, q = (e & 15) << 3;
    const int j = idxr[r];
    *(short8*)(&Ms[r * 136 + q]) = *(const short8*)(P3g + (size_t)(bbase + j) * 128 + q);
  }
  const float p1c0 = P1g[(size_t)bidx * 128 + w * 32 + rr];
  const float p1c1 = P1g[(size_t)bidx * 128 + w * 32 + 16 + rr];
  __syncthreads();                                        // B1

  // residual capture (wave-own cols) + acc-init
  f32x4 acc[3][2];
  float res[3][2][4];
  #pragma unroll
  for (int m = 0; m < 3; ++m)
    #pragma unroll
    for (int c = 0; c < 2; ++c)
      #pragma unroll
      for (int r = 0; r < 4; ++r) {
        const int row = m * 16 + g4 + r;
        const int col = w * 32 + c * 16 + rr;
        acc[m][c][r] = (c ? p1c1 : p1c0) + bf2f(Ms[row * 136 + col]);
        res[m][c][r] = bf2f(Xs[row * 136 + col]);
      }

  gemm_tiles<4, 3, 8>(Xs, 136, Wmidp, lane, w, acc);
  #pragma unroll
  for (int m = 0; m < 3; ++m)
    #pragma unroll
    for (int c = 0; c < 2; ++c)
      #pragma unroll
      for (int r = 0; r < 4; ++r) {
        const int row = m * 16 + g4 + r;
        Ms[row * 136 + w * 32 + c * 16 + rr] = f2bf(gelu_f(acc[m][c][r]));
      }
  __syncthreads();                                        // B2

  const f32x4 zf = {0.f, 0.f, 0.f, 0.f};
  #pragma unroll
  for (int m = 0; m < 3; ++m) { acc[m][0] = zf; acc[m][1] = zf; }
  gemm_tiles<4, 3, 8>(Ms, 136, W12p, lane, w, acc);
  {
    const float b0 = W12b[w * 32 + rr], b1 = W12b[w * 32 + 16 + rr];
    #pragma unroll
    for (int m = 0; m < 3; ++m)
      #pragma unroll
      for (int c = 0; c < 2; ++c)
        #pragma unroll
        for (int r = 0; r < 4; ++r) {
          const int row = m * 16 + g4 + r;
          Xs[row * 136 + w * 32 + c * 16 + rr] = f2bf(gelu_f(acc[m][c][r] + (c ? b1 : b0)));
        }
  }
  __syncthreads();                                        // B3

  #pragma unroll
  for (int m = 0; m < 3; ++m) { acc[m][0] = zf; acc[m][1] = zf; }
  gemm_tiles<4, 3, 8>(Xs, 136, W13p, lane, w, acc);

  {
    const float b0 = W13b[w * 32 + rr], b1 = W13b[w * 32 + 16 + rr];
    #pragma unroll
    for (int m = 0; m < 3; ++m)
      #pragma unroll
      for (int r = 0; r < 4; ++r) {
        const int row = m * 16 + g4 + r;
        acc[m][0][r] += b0 + res[m][0][r];
        acc[m][1][r] += b1 + res[m][1][r];
        float s = acc[m][0][r] + acc[m][1][r];
        float q2 = acc[m][0][r] * acc[m][0][r] + acc[m][1][r] * acc[m][1][r];
        s += __shfl_xor(s, 1); q2 += __shfl_xor(q2, 1);
        s += __shfl_xor(s, 2); q2 += __shfl_xor(q2, 2);
        s += __shfl_xor(s, 4); q2 += __shfl_xor(q2, 4);
        s += __shfl_xor(s, 8); q2 += __shfl_xor(q2, 8);
        if ((lane & 15) == 0) { sums[row * 4 + w] = s; sqs[row * 4 + w] = q2; }
      }
  }
  __syncthreads();                                        // B4
  if (tid < 48) {
    const float s = sums[tid * 4] + sums[tid * 4 + 1] + sums[tid * 4 + 2] + sums[tid * 4 + 3];
    const float q2 = sqs[tid * 4] + sqs[tid * 4 + 1] + sqs[tid * 4 + 2] + sqs[tid * 4 + 3];
    const float mean = s * (1.f / 128.f);
    mr[tid * 2] = mean;
    mr[tid * 2 + 1] = rsqrtf(q2 * (1.f / 128.f) - mean * mean + 1e-5f);
  }
  __syncthreads();                                        // B5
  {
    const float g0 = ln3g[w * 32 + rr], g1 = ln3g[w * 32 + 16 + rr];
    const float be0 = ln3b[w * 32 + rr], be1 = ln3b[w * 32 + 16 + rr];
    #pragma unroll
    for (int m = 0; m < 3; ++m)
      #pragma unroll
      for (int r = 0; r < 4; ++r) {
        const int row = m * 16 + g4 + r;
        const float mean = mr[row * 2], rstd = mr[row * 2 + 1];
        const size_t base = (size_t)bidx * 6144 + (size_t)row * 128 + w * 32 + rr;
        outE[base]      = (acc[m][0][r] - mean) * rstd * g0 + be0;
        outE[base + 16] = (acc[m][1][r] - mean) * rstd * g1 + be1;
      }
  }
}

extern "C" void kernel_launch(void* const* d_in, const int* in_sizes, int n_in,
                              void* d_out, int out_size, void* d_ws, size_t ws_size,
                              hipStream_t stream) {
  const float* hV    = (const float*)d_in[0];
  const float* hE    = (const float*)d_in[1];
  const int*   Eidx  = (const int*)d_in[2];
  const float* maskV = (const float*)d_in[3];
  const float* maskA = (const float*)d_in[4];
  const float* W1w  = (const float*)d_in[5];  const float* W1b  = (const float*)d_in[6];
  const float* W2w  = (const float*)d_in[7];  const float* W2b  = (const float*)d_in[8];
  const float* W3w  = (const float*)d_in[9];  const float* W3b  = (const float*)d_in[10];
  const float* W11w = (const float*)d_in[11]; const float* W11b = (const float*)d_in[12];
  const float* W12w = (const float*)d_in[13]; const float* W12b = (const float*)d_in[14];
  const float* W13w = (const float*)d_in[15]; const float* W13b = (const float*)d_in[16];
  const float* Winw = (const float*)d_in[17]; const float* Winb = (const float*)d_in[18];
  const float* Woutw= (const float*)d_in[19]; const float* Woutb= (const float*)d_in[20];
  const float* ln1g = (const float*)d_in[21]; const float* ln1b = (const float*)d_in[22];
  const float* ln2g = (const float*)d_in[23]; const float* ln2b = (const float*)d_in[24];
  const float* ln3g = (const float*)d_in[25]; const float* ln3b = (const float*)d_in[26];

  float* outV = (float*)d_out;                       // [4096,128]
  float* outE = outV + (size_t)4096 * 128;           // [4096*48,128]

  char* ws = (char*)d_ws;
  float* hVn1 = (float*)ws;                                  // 2 MB
  float* P1   = (float*)(ws + (size_t)2 * 1024 * 1024);      // 2 MB
  unsigned short* P3 = (unsigned short*)(ws + (size_t)4 * 1024 * 1024);  // 1 MB
  unsigned short* Wp = (unsigned short*)(ws + (size_t)5 * 1024 * 1024);  // 576 KB
  unsigned short* hEb = (unsigned short*)(ws + (size_t)6 * 1024 * 1024); // 48 MB bf16

  const size_t NEED = (size_t)6 * 1024 * 1024 + (size_t)4096 * 48 * 128 * 2;
  const bool heb = ws_size >= NEED;

  const unsigned short* W1top_p  = Wp;
  const unsigned short* W1mid_p  = Wp + (size_t)2048 * 8;
  const unsigned short* W1bot_p  = Wp + (size_t)4096 * 8;
  const unsigned short* W2p      = Wp + (size_t)6144 * 8;
  const unsigned short* W11top_p = Wp + (size_t)10240 * 8;
  const unsigned short* W11mid_p = Wp + (size_t)12288 * 8;
  const unsigned short* W11bot_p = Wp + (size_t)14336 * 8;
  const unsigned short* W12p     = Wp + (size_t)16384 * 8;
  const unsigned short* W13p     = Wp + (size_t)18432 * 8;
  const unsigned short* Winp     = Wp + (size_t)20480 * 8;
  const unsigned short* Woutp    = Wp + (size_t)28672 * 8;

  k_pack<<<144, 256, 0, stream>>>(W1w, W2w, W3w, W11w, W12w, W13w, Winw, Woutw, Wp);
  k_pre<<<256, 256, 0, stream>>>(hV, W1top_p, W1bot_p, W1b, P1, P3);

  if (heb)
    k_node_t<true><<<4096, 256, 0, stream>>>(hV, hE, hEb, Eidx, maskA, P1, P3,
                                             W1mid_p, W2p, W2b, W3w, W3b,
                                             ln1g, ln1b, hVn1);
  else
    k_node_t<false><<<4096, 256, 0, stream>>>(hV, hE, hEb, Eidx, maskA, P1, P3,
                                              W1mid_p, W2p, W2b, W3w, W3b,
                                              ln1g, ln1b, hVn1);

  k_ffn<<<256, 256, 0, stream>>>(hVn1, Winp, Winb, Woutp, Woutb,
                                 ln2g, ln2b, maskV,
                                 W11top_p, W11bot_p, W11b,
                                 outV, P1, P3);

  if (heb)
    k_edge_t<true><<<4096, 256, 0, stream>>>(hE, hEb, Eidx, P1, P3,
                                             W11mid_p, W12p, W12b, W13p, W13b,
                                             ln3g, ln3b, outE);
  else
    k_edge_t<false><<<4096, 256, 0, stream>>>(hE, hEb, Eidx, P1, P3,
                                              W11mid_p, W12p, W12b, W13p, W13b,
                                              ln3g, ln3b, outE);
}